// Round 1
// baseline (656.702 us; speedup 1.0000x reference)
//
#include <hip/hip_runtime.h>

#define BDIM 32
#define SDIM 512
#define DDIM 1024
#define ADIM 4
#define NCAND 65536

__global__ void zero_counts_kernel(float* counts) {
    int i = threadIdx.x;
    if (i < BDIM) counts[i] = 0.0f;
}

__global__ __launch_bounds__(256) void cand_repr_kernel(
    const float* __restrict__ word_repr,   // [B,S,D]
    const int*   __restrict__ cand_idx,    // [N,3]
    const int*   __restrict__ anchor_loc,  // [B,S,A,2]
    const int*   __restrict__ anchor_cls,  // [B,S,A]
    float* __restrict__ out_repr,          // [N,D]
    float* __restrict__ out_label,         // [N]
    float* __restrict__ out_counts,        // [B]
    float* __restrict__ out_valid,         // [N]
    float* __restrict__ out_loc)           // [N,2]
{
    const int n   = blockIdx.x;
    const int tid = threadIdx.x;

    // Same-address loads across the block -> broadcast from cache; no barrier.
    const int b = cand_idx[n * 3 + 0];
    const int w = cand_idx[n * 3 + 1];
    const int a = cand_idx[n * 3 + 2];
    const int base = (b * SDIM + w) * ADIM + a;
    const int sid = anchor_loc[base * 2 + 0];
    const int eid = anchor_loc[base * 2 + 1];
    const int len = eid - sid;            // in [0, 8]
    const bool valid = len > 0;

    if (tid == 0) {
        out_label[n]     = valid ? (float)anchor_cls[base] : -1.0f;
        out_valid[n]     = valid ? 1.0f : 0.0f;
        out_loc[n*2 + 0] = valid ? (float)sid : 0.0f;
        out_loc[n*2 + 1] = valid ? (float)eid : 0.0f;
        if (valid) atomicAdd(&out_counts[b], 1.0f);
    }

    // Mean-pool span rows: contiguous 4KB rows, thread tid owns float4 #tid.
    const float4* __restrict__ src =
        (const float4*)(word_repr + ((size_t)b * SDIM + sid) * DDIM);
    float4 acc = make_float4(0.f, 0.f, 0.f, 0.f);
    #pragma unroll 1
    for (int s = 0; s < len; ++s) {
        float4 v = src[(size_t)s * (DDIM / 4) + tid];
        acc.x += v.x; acc.y += v.y; acc.z += v.z; acc.w += v.w;
    }
    const float scale = valid ? 1.0f / (float)len : 0.0f;
    acc.x *= scale; acc.y *= scale; acc.z *= scale; acc.w *= scale;

    float4* __restrict__ dst = (float4*)(out_repr + (size_t)n * DDIM);
    dst[tid] = acc;
}

extern "C" void kernel_launch(void* const* d_in, const int* in_sizes, int n_in,
                              void* d_out, int out_size, void* d_ws, size_t ws_size,
                              hipStream_t stream) {
    const float* word_repr  = (const float*)d_in[0];
    const int*   cand_idx   = (const int*)d_in[1];
    const int*   anchor_loc = (const int*)d_in[2];
    const int*   anchor_cls = (const int*)d_in[3];

    float* out = (float*)d_out;
    float* out_repr   = out;                                   // N*D
    float* out_label  = out_repr  + (size_t)NCAND * DDIM;      // N
    float* out_counts = out_label + NCAND;                     // B
    float* out_valid  = out_counts + BDIM;                     // N
    float* out_loc    = out_valid + NCAND;                     // N*2

    zero_counts_kernel<<<1, 64, 0, stream>>>(out_counts);
    cand_repr_kernel<<<NCAND, 256, 0, stream>>>(
        word_repr, cand_idx, anchor_loc, anchor_cls,
        out_repr, out_label, out_counts, out_valid, out_loc);
}